// Round 4
// baseline (37.045 us; speedup 1.0000x reference)
//
#include <hip/hip_runtime.h>

#define FH 50
#define FW 50
#define FC 512
#define NROI 1024
#define ROWPITCH (FW * FC)   // 25600 floats per feature row

typedef float f4v __attribute__((ext_vector_type(4)));

__device__ __forceinline__ float4 lerp4(float4 a, float4 b, float t) {
    float4 r;
    r.x = fmaf(t, b.x - a.x, a.x);
    r.y = fmaf(t, b.y - a.y, a.y);
    r.z = fmaf(t, b.z - a.z, a.z);
    r.w = fmaf(t, b.w - a.w, a.w);
    return r;
}

__device__ __forceinline__ float4 max44(float4 a, float4 b) {
    float4 r;
    r.x = fmaxf(a.x, b.x);
    r.y = fmaxf(a.y, b.y);
    r.z = fmaxf(a.z, b.z);
    r.w = fmaxf(a.w, b.w);
    return r;
}

// One wave per (roi n, pooled row py, channel half). Column-major walk over
// the <=15 distinct feature columns with an explicit DEPTH-2 software
// pipeline: raw loads for column s+2 are issued before column s's vertical
// lerp + sample emission, so L2/L3 latency hides under ~2 columns of compute.
__global__ __launch_bounds__(256) void roi_pool_kernel(
    const float* __restrict__ feature,   // (1,50,50,512)
    const float* __restrict__ rois,      // (1024,4)
    const int*   __restrict__ img_size,  // (2)
    float*       __restrict__ out)       // (1024,7,7,512)
{
    int wid  = (blockIdx.x * 256 + threadIdx.x) >> 6;
    wid = __builtin_amdgcn_readfirstlane(wid);   // wave-uniform -> SGPR
    int lane = threadIdx.x & 63;

    int n    = wid / 14;
    int rem  = wid - n * 14;
    int py   = rem >> 1;
    int half = rem & 1;

    float ih = (float)img_size[0];
    float iw = (float)img_size[1];
    const float* rp = rois + (size_t)n * 4;
    float x1 = rp[0] / iw, y1 = rp[1] / ih, x2 = rp[2] / iw, y2 = rp[3] / ih;

    const float HM1 = 49.0f, WM1 = 49.0f;
    float sy = (y2 - y1) * HM1 / 13.0f;   // < 1 for this distribution
    float sx = (x2 - x1) * WM1 / 13.0f;   // < 1
    float oy = y1 * HM1;
    float ox = x1 * WM1;

    // y geometry (uniform for the wave)
    float iy0 = oy + (float)(2 * py)     * sy;
    float iy1 = oy + (float)(2 * py + 1) * sy;
    float fy0 = floorf(iy0), fy1 = floorf(iy1);
    float ly0 = iy0 - fy0,   ly1 = iy1 - fy1;
    int t0 = min(max((int)fy0, 0), FH - 1);
    int b0 = min(max((int)fy0 + 1, 0), FH - 1);
    int t1 = min(max((int)fy1, 0), FH - 1);
    int b1 = min(max((int)fy1 + 1, 0), FH - 1);
    bool vy0 = (iy0 >= 0.0f) && (iy0 <= HM1);
    bool vy1 = (iy1 >= 0.0f) && (iy1 <= HM1);
    bool sameRows = (t1 == t0) && (b1 == b0);

    // x extent: distinct columns c0u .. c0u+ncols-1  (ncols <= 15)
    int c0u   = (int)floorf(ox);
    int lumax = (int)floorf(ox + 13.0f * sx);
    int ncols = lumax + 2 - c0u;

    const float* fbase = feature + half * 256 + lane * 4;
    float* obase = out + ((size_t)n * 49 + (size_t)py * 7) * FC + half * 256 + lane * 4;

#define ISSUE(slot, A, B, C, D)                                                   \
    {                                                                             \
        int cc = min(c0u + (slot), FW - 1);                                       \
        const float* p = fbase + (size_t)cc * FC;                                 \
        A = *reinterpret_cast<const float4*>(p + (size_t)t0 * ROWPITCH);          \
        B = *reinterpret_cast<const float4*>(p + (size_t)b0 * ROWPITCH);          \
        if (!sameRows) {                                                          \
            C = *reinterpret_cast<const float4*>(p + (size_t)t1 * ROWPITCH);      \
            D = *reinterpret_cast<const float4*>(p + (size_t)b1 * ROWPITCH);      \
        }                                                                         \
    }

    float4 p0A, p0B, p0C, p0D;   // pending raw loads, even slots
    float4 p1A, p1B, p1C, p1D;   // pending raw loads, odd slots
    ISSUE(0, p0A, p0B, p0C, p0D);
    ISSUE(1, p1A, p1B, p1C, p1D);

    float4 Vp0, Vp1;             // prev column vertical-lerped values
    float4 m = make_float4(0.f, 0.f, 0.f, 0.f);
    int j = 0;

#define CONSUME(scol)                                                             \
    while (j < 14) {                                                              \
        float ix = ox + (float)j * sx;                                            \
        float fx = floorf(ix);                                                    \
        if ((int)fx != (scol) + c0u - 1) break;                                   \
        float lx = ix - fx;                                                       \
        float4 s0 = lerp4(Vp0, Vc0, lx);                                          \
        float4 s1 = lerp4(Vp1, Vc1, lx);                                          \
        bool vx = (ix >= 0.0f) && (ix <= WM1);                                    \
        if (!(vx && vy0)) s0 = make_float4(0.f, 0.f, 0.f, 0.f);                   \
        if (!(vx && vy1)) s1 = make_float4(0.f, 0.f, 0.f, 0.f);                   \
        float4 sm = max44(s0, s1);                                                \
        if (j & 1) {                                                              \
            m = max44(m, sm);                                                     \
            __builtin_nontemporal_store(*reinterpret_cast<f4v*>(&m),              \
                reinterpret_cast<f4v*>(obase + (size_t)(j >> 1) * FC));           \
        } else {                                                                  \
            m = sm;                                                               \
        }                                                                         \
        ++j;                                                                      \
    }

    for (int s = 0; s < ncols; s += 2) {
        {   // even slot s: consume raw p0, refill with slot s+2
            float4 rA = p0A, rB = p0B, rC = p0C, rD = p0D;
            if (s + 2 < ncols) ISSUE(s + 2, p0A, p0B, p0C, p0D);
            float4 Vc0 = lerp4(rA, rB, ly0);
            float4 Vc1 = sameRows ? lerp4(rA, rB, ly1) : lerp4(rC, rD, ly1);
            if (s >= 1) { CONSUME(s); }
            Vp0 = Vc0; Vp1 = Vc1;
        }
        if (s + 1 < ncols) {   // odd slot s+1: consume raw p1, refill slot s+3
            float4 rA = p1A, rB = p1B, rC = p1C, rD = p1D;
            if (s + 3 < ncols) ISSUE(s + 3, p1A, p1B, p1C, p1D);
            float4 Vc0 = lerp4(rA, rB, ly0);
            float4 Vc1 = sameRows ? lerp4(rA, rB, ly1) : lerp4(rC, rD, ly1);
            CONSUME(s + 1);
            Vp0 = Vc0; Vp1 = Vc1;
        }
    }

#undef ISSUE
#undef CONSUME
}

extern "C" void kernel_launch(void* const* d_in, const int* in_sizes, int n_in,
                              void* d_out, int out_size, void* d_ws, size_t ws_size,
                              hipStream_t stream) {
    const float* feature  = (const float*)d_in[0];
    const float* rois     = (const float*)d_in[1];
    const int*   img_size = (const int*)d_in[2];
    float* out = (float*)d_out;

    // 1024 rois * 14 (py, half) waves = 14336 waves, 4 waves/block
    int blocks = NROI * 14 / 4;   // 3584
    roi_pool_kernel<<<blocks, 256, 0, stream>>>(feature, rois, img_size, out);
}